// Round 2
// baseline (455.224 us; speedup 1.0000x reference)
//
#include <hip/hip_runtime.h>
#include <hip/hip_bf16.h>
#include <math.h>

// Problem constants
#define BB   4
#define HH   16
#define LL   4096
#define DKK  64
#define MM   8      // LOG_LK == LOG_L
#define NCC  3
#define BH   (BB*HH)            // 64
#define ROWS_PER_CHUNK 512
#define NCHUNK (LL/ROWS_PER_CHUNK)  // 8
#define CTX_ELEMS (BB*HH*LL*DKK)    // 16777216

// ws layout (floats): [3][BH][8][64] partial sums, order: 0=K, 1=V, 2=Q
// total = 3*64*512 = 98304 floats = 393216 bytes

// ---------------------------------------------------------------------------
// Kernel 1: shrink reductions.  For X in {K,V,Q}:
//   ws[x][bh][m][d] = sum_k X[bh][k][d] * w[m][k]      (bias added later)
// grid = 3 * 64 * 8 = 1536 blocks, 256 threads
// ---------------------------------------------------------------------------
__global__ __launch_bounds__(256) void shrink_kernel(
    const float* __restrict__ Q, const float* __restrict__ K,
    const float* __restrict__ V,
    const float* __restrict__ skw, const float* __restrict__ svw,
    const float* __restrict__ sqw,
    float* __restrict__ ws)
{
    // 48KB LDS: [0..4095] weights chunk [512][8]; [4096..12287] reduce buf [256][32]
    __shared__ float lds[12288];

    int bx    = blockIdx.x;
    int input = bx >> 9;        // 0=K, 1=V, 2=Q
    int rem   = bx & 511;
    int bh    = rem >> 3;
    int chunk = rem & 7;

    const float* X; const float* W;
    if (input == 0)      { X = K; W = skw; }
    else if (input == 1) { X = V; W = svw; }
    else                 { X = Q; W = sqw; }

    int t  = threadIdx.x;
    int k0 = chunk * ROWS_PER_CHUNK;

    // stage weight chunk: W[m][k0+k] -> lds[k*8+m]
    #pragma unroll
    for (int m = 0; m < MM; ++m)
        for (int k = t; k < ROWS_PER_CHUNK; k += 256)
            lds[k*8 + m] = W[m*LL + k0 + k];
    __syncthreads();

    int d4     = (t & 15) * 4;   // which 4 d-columns
    int stripe = t >> 4;         // 0..15, which row within a 16-row slab

    const float* base = X + (size_t)bh * LL * DKK;

    float4 acc[MM];
    #pragma unroll
    for (int m = 0; m < MM; ++m) acc[m] = make_float4(0.f, 0.f, 0.f, 0.f);

    for (int i = 0; i < ROWS_PER_CHUNK/16; ++i) {   // 32 iterations
        int kp = i*16 + stripe;
        float4 v = *reinterpret_cast<const float4*>(
            base + (size_t)(k0 + kp) * DKK + d4);
        #pragma unroll
        for (int m = 0; m < MM; ++m) {
            float w = lds[kp*8 + m];
            acc[m].x = fmaf(v.x, w, acc[m].x);
            acc[m].y = fmaf(v.y, w, acc[m].y);
            acc[m].z = fmaf(v.z, w, acc[m].z);
            acc[m].w = fmaf(v.w, w, acc[m].w);
        }
    }
    __syncthreads();

    // partials -> LDS: red[t][m*4+j]
    float* red = lds + 4096;
    #pragma unroll
    for (int m = 0; m < MM; ++m) {
        red[t*32 + m*4 + 0] = acc[m].x;
        red[t*32 + m*4 + 1] = acc[m].y;
        red[t*32 + m*4 + 2] = acc[m].z;
        red[t*32 + m*4 + 3] = acc[m].w;
    }
    __syncthreads();

    // reduce over 16 stripes; 512 outputs (m,d)
    float* wsb = ws + ((size_t)input * BH + bh) * 512;
    for (int out = t; out < 512; out += 256) {
        int m  = out >> 6;
        int d  = out & 63;
        int dg = d >> 2, dj = d & 3;
        float s = 0.f;
        #pragma unroll
        for (int st = 0; st < 16; ++st)
            s += red[(st*16 + dg)*32 + m*4 + dj];
        atomicAdd(wsb + out, s);
    }
}

// ---------------------------------------------------------------------------
// Kernel 2: cluster / loss math.  1 block, 256 threads.
// ---------------------------------------------------------------------------
__global__ __launch_bounds__(256) void loss_kernel(
    const float* __restrict__ ws,
    const float* __restrict__ skb, const float* __restrict__ sqb,
    const float* __restrict__ pk_w, const float* __restrict__ pk_b,
    const float* __restrict__ pq_w, const float* __restrict__ pq_b,
    const float* __restrict__ qp_w, const float* __restrict__ qp_b,
    const float* __restrict__ kp_w, const float* __restrict__ kp_b,
    float* __restrict__ out_loss)
{
    __shared__ float ckp_s[BB][NCC];
    __shared__ float cqp_s[BB][NCC];

    int t = threadIdx.x;
    // 24 groups (12 for K-path, 12 for Q-path) x 8 lanes
    int group = t >> 3;
    int lane  = t & 7;
    if (group < 24) {
        int isQ = (group >= 12);
        int g   = group % 12;
        int b   = g / NCC;
        int c   = g % NCC;
        const float* xs   = ws + (size_t)(isQ ? 2 : 0) * BH * 512 + (size_t)b * 8192;
        const float* bias = isQ ? sqb : skb;
        const float* pw   = (isQ ? pq_w : pk_w) + (size_t)c * 8192;
        float accum = 0.f;
        for (int j = lane; j < 8192; j += 8) {
            float x = xs[j] + bias[(j >> 6) & 7];
            accum = fmaf(x, pw[j], accum);
        }
        accum += __shfl_xor(accum, 1);
        accum += __shfl_xor(accum, 2);
        accum += __shfl_xor(accum, 4);
        if (lane == 0) {
            float pb = (isQ ? pq_b : pk_b)[c];
            float r  = accum + pb;
            r = r > 0.f ? r : 0.f;       // relu
            if (isQ) cqp_s[b][c] = r; else ckp_s[b][c] = r;
        }
    }
    __syncthreads();

    if (t == 0) {
        float cq[BB][NCC], ck[BB][NCC];
        for (int b = 0; b < BB; ++b) {
            float lq[NCC], lk[NCC];
            for (int c = 0; c < NCC; ++c) {
                float sq = qp_b[c], sk = kp_b[c];
                for (int c2 = 0; c2 < NCC; ++c2) {
                    sq = fmaf(cqp_s[b][c2], qp_w[c*NCC + c2], sq);
                    sk = fmaf(ckp_s[b][c2], kp_w[c*NCC + c2], sk);
                }
                lq[c] = sq; lk[c] = sk;
            }
            // softmax
            float mq = fmaxf(fmaxf(lq[0], lq[1]), lq[2]);
            float mk = fmaxf(fmaxf(lk[0], lk[1]), lk[2]);
            float zq = 0.f, zk = 0.f;
            for (int c = 0; c < NCC; ++c) {
                cq[b][c] = expf(lq[c] - mq); zq += cq[b][c];
                ck[b][c] = expf(lk[c] - mk); zk += ck[b][c];
            }
            for (int c = 0; c < NCC; ++c) { cq[b][c] /= zq; ck[b][c] /= zk; }
        }
        // mu = mean_b cluster_q ; sigma = softplus(std_b(cluster_k, ddof=1))
        float mu[NCC], mk_[NCC], sigma[NCC];
        for (int c = 0; c < NCC; ++c) {
            float s1 = 0.f, s2 = 0.f;
            for (int b = 0; b < BB; ++b) { s1 += cq[b][c]; s2 += ck[b][c]; }
            mu[c]  = s1 * 0.25f;
            mk_[c] = s2 * 0.25f;
        }
        for (int c = 0; c < NCC; ++c) {
            float v = 0.f;
            for (int b = 0; b < BB; ++b) {
                float d = ck[b][c] - mk_[c];
                v = fmaf(d, d, v);
            }
            float stdv = sqrtf(v / (BB - 1));
            sigma[c] = log1pf(expf(stdv));   // softplus
        }
        const float HALF_LOG_2PI = 0.9189385332046727f;
        float sum_logp = 0.f;
        for (int b = 0; b < BB; ++b)
            for (int c = 0; c < NCC; ++c) {
                float z = (ck[b][c] - mu[c]) / sigma[c];
                sum_logp += -0.5f*z*z - logf(sigma[c]) - HALF_LOG_2PI;
            }
        // ce = mean_b( -sum_c cq*log_softmax(cq) )
        float ce = 0.f;
        for (int b = 0; b < BB; ++b) {
            float mx = fmaxf(fmaxf(cq[b][0], cq[b][1]), cq[b][2]);
            float z = 0.f;
            for (int c = 0; c < NCC; ++c) z += expf(cq[b][c] - mx);
            float lse = mx + logf(z);
            float s = 0.f;
            for (int c = 0; c < NCC; ++c) s += cq[b][c] * (cq[b][c] - lse);
            ce += -s;
        }
        ce *= 0.25f;
        float loss = -(sum_logp / (BB * NCC)) + ce;
        out_loss[0] = loss;
    }
}

// ---------------------------------------------------------------------------
// Kernel 3: broadcast context.  attn == 1/8 uniformly =>
//   ctx[b,h,l,d] = (1/8) * sum_m (Vs_sum[b,h,m,d] + svb[m])   (same for all l)
// grid = 64 * 16 = 1024 blocks, 256 threads; each block writes 256 l-rows.
// ---------------------------------------------------------------------------
__global__ __launch_bounds__(256) void broadcast_kernel(
    const float* __restrict__ ws, const float* __restrict__ svb,
    float* __restrict__ out)
{
    int bx = blockIdx.x;
    int bh = bx >> 4;
    int lc = bx & 15;
    int t  = threadIdx.x;
    int d4     = (t & 15) * 4;
    int stripe = t >> 4;

    const float* vs = ws + ((size_t)1 * BH + bh) * 512;   // V partition
    float bias = 0.f;
    #pragma unroll
    for (int m = 0; m < MM; ++m) bias += svb[m];
    bias *= 0.125f;

    float4 c = make_float4(bias, bias, bias, bias);
    #pragma unroll
    for (int m = 0; m < MM; ++m) {
        c.x += 0.125f * vs[m*64 + d4 + 0];
        c.y += 0.125f * vs[m*64 + d4 + 1];
        c.z += 0.125f * vs[m*64 + d4 + 2];
        c.w += 0.125f * vs[m*64 + d4 + 3];
    }

    float* obase = out + (size_t)bh * LL * DKK + (size_t)lc * 256 * DKK;
    #pragma unroll
    for (int i = 0; i < 16; ++i) {
        int l = i*16 + stripe;
        *reinterpret_cast<float4*>(obase + (size_t)l * DKK + d4) = c;
    }
}

// ---------------------------------------------------------------------------
extern "C" void kernel_launch(void* const* d_in, const int* in_sizes, int n_in,
                              void* d_out, int out_size, void* d_ws, size_t ws_size,
                              hipStream_t stream) {
    const float* Q    = (const float*)d_in[0];
    const float* K    = (const float*)d_in[1];
    const float* V    = (const float*)d_in[2];
    const float* skw  = (const float*)d_in[3];
    const float* skb  = (const float*)d_in[4];
    const float* svw  = (const float*)d_in[5];
    const float* svb  = (const float*)d_in[6];
    const float* sqw  = (const float*)d_in[7];
    const float* sqb  = (const float*)d_in[8];
    const float* pk_w = (const float*)d_in[9];
    const float* pk_b = (const float*)d_in[10];
    const float* pq_w = (const float*)d_in[11];
    const float* pq_b = (const float*)d_in[12];
    const float* qp_w = (const float*)d_in[13];
    const float* qp_b = (const float*)d_in[14];
    const float* kp_w = (const float*)d_in[15];
    const float* kp_b = (const float*)d_in[16];

    float* out = (float*)d_out;
    float* ws  = (float*)d_ws;

    // zero the atomic accumulators (ws is poisoned 0xAA before every call)
    hipMemsetAsync(ws, 0, (size_t)3 * BH * 512 * sizeof(float), stream);

    shrink_kernel<<<dim3(3 * BH * NCHUNK), dim3(256), 0, stream>>>(
        Q, K, V, skw, svw, sqw, ws);

    loss_kernel<<<dim3(1), dim3(256), 0, stream>>>(
        ws, skb, sqb, pk_w, pk_b, pq_w, pq_b, qp_w, qp_b, kp_w, kp_b,
        out + (size_t)CTX_ELEMS);

    broadcast_kernel<<<dim3(BH * 16), dim3(256), 0, stream>>>(ws, svb, out);
}

// Round 4
// 276.824 us; speedup vs baseline: 1.6445x; 1.6445x over previous
//
#include <hip/hip_runtime.h>
#include <hip/hip_bf16.h>
#include <math.h>

// Problem constants
#define BB   4
#define HH   16
#define LL   4096
#define DKK  64
#define MM   8      // LOG_LK == LOG_L
#define NCC  3
#define BH   (BB*HH)            // 64
#define ROWS_PER_CHUNK 512
#define NCHUNK (LL/ROWS_PER_CHUNK)  // 8
#define CTX_ELEMS (BB*HH*LL*DKK)    // 16777216

// ws layout (floats):
//   [0 .. 98303]   : [3][BH][8][64] shrink partial sums, order: 0=K, 1=V, 2=Q
//   [98304..98327] : 24 relu'd cluster dot products (12 K-path, 12 Q-path)
#define DOTS_OFF 98304

// ---------------------------------------------------------------------------
// Kernel 1: shrink reductions.  For X in {K,V,Q}:
//   ws[x][bh][m][d] = sum_k X[bh][k][d] * w[m][k]      (bias added later)
// grid = 3 * 64 * 8 = 1536 blocks, 256 threads
// ---------------------------------------------------------------------------
__global__ __launch_bounds__(256) void shrink_kernel(
    const float* __restrict__ Q, const float* __restrict__ K,
    const float* __restrict__ V,
    const float* __restrict__ skw, const float* __restrict__ svw,
    const float* __restrict__ sqw,
    float* __restrict__ ws)
{
    // 48KB LDS: [0..4095] weights chunk [512][8]; [4096..12287] reduce buf [256][32]
    __shared__ float lds[12288];

    int bx    = blockIdx.x;
    int input = bx >> 9;        // 0=K, 1=V, 2=Q
    int rem   = bx & 511;
    int bh    = rem >> 3;
    int chunk = rem & 7;

    const float* X; const float* W;
    if (input == 0)      { X = K; W = skw; }
    else if (input == 1) { X = V; W = svw; }
    else                 { X = Q; W = sqw; }

    int t  = threadIdx.x;
    int k0 = chunk * ROWS_PER_CHUNK;

    // stage weight chunk: W[m][k0+k] -> lds[k*8+m]
    #pragma unroll
    for (int m = 0; m < MM; ++m)
        for (int k = t; k < ROWS_PER_CHUNK; k += 256)
            lds[k*8 + m] = W[m*LL + k0 + k];
    __syncthreads();

    int d4     = (t & 15) * 4;   // which 4 d-columns
    int stripe = t >> 4;         // 0..15, which row within a 16-row slab

    const float* base = X + (size_t)bh * LL * DKK;

    float4 acc[MM];
    #pragma unroll
    for (int m = 0; m < MM; ++m) acc[m] = make_float4(0.f, 0.f, 0.f, 0.f);

    for (int i = 0; i < ROWS_PER_CHUNK/16; ++i) {   // 32 iterations
        int kp = i*16 + stripe;
        float4 v = *reinterpret_cast<const float4*>(
            base + (size_t)(k0 + kp) * DKK + d4);
        // weights: 8 consecutive floats at lds[kp*8], 32B-aligned ->
        // two ds_read_b128, broadcast within 16-lane groups, stripe banks 0/8/16/24
        float4 w0 = *reinterpret_cast<const float4*>(&lds[kp*8]);
        float4 w1 = *reinterpret_cast<const float4*>(&lds[kp*8 + 4]);
        float wm[MM] = {w0.x, w0.y, w0.z, w0.w, w1.x, w1.y, w1.z, w1.w};
        #pragma unroll
        for (int m = 0; m < MM; ++m) {
            float w = wm[m];
            acc[m].x = fmaf(v.x, w, acc[m].x);
            acc[m].y = fmaf(v.y, w, acc[m].y);
            acc[m].z = fmaf(v.z, w, acc[m].z);
            acc[m].w = fmaf(v.w, w, acc[m].w);
        }
    }
    __syncthreads();

    // partials -> LDS: red[t][m*4+j]
    float* red = lds + 4096;
    #pragma unroll
    for (int m = 0; m < MM; ++m) {
        red[t*32 + m*4 + 0] = acc[m].x;
        red[t*32 + m*4 + 1] = acc[m].y;
        red[t*32 + m*4 + 2] = acc[m].z;
        red[t*32 + m*4 + 3] = acc[m].w;
    }
    __syncthreads();

    // reduce over 16 stripes; 512 outputs (m,d)
    float* wsb = ws + ((size_t)input * BH + bh) * 512;
    for (int out = t; out < 512; out += 256) {
        int m  = out >> 6;
        int d  = out & 63;
        int dg = d >> 2, dj = d & 3;
        float s = 0.f;
        #pragma unroll
        for (int st = 0; st < 16; ++st)
            s += red[(st*16 + dg)*32 + m*4 + dj];
        atomicAdd(wsb + out, s);
    }
}

// ---------------------------------------------------------------------------
// Kernel 2: 24 cluster dot-products, one block each.
//   idx < 12:  K-path  (b = idx/3, c = idx%3): relu( (Ks+skb) . pk_w[c] + pk_b[c] )
//   idx >= 12: Q-path  similarly with sqb/pq_w/pq_b
// Each dot is over 8192 elements = [h=16][m=8][d=64]; bias depends on m only.
// ---------------------------------------------------------------------------
__global__ __launch_bounds__(256) void dot_kernel(
    const float* __restrict__ ws,
    const float* __restrict__ skb, const float* __restrict__ sqb,
    const float* __restrict__ pk_w, const float* __restrict__ pk_b,
    const float* __restrict__ pq_w, const float* __restrict__ pq_b,
    float* __restrict__ dots)
{
    __shared__ float red[4];
    int idx = blockIdx.x;
    int isQ = idx >= 12;
    int g   = idx - (isQ ? 12 : 0);
    int b   = g / NCC;
    int c   = g % NCC;

    const float* xs   = ws + (size_t)(isQ ? 2 : 0) * (BH * 512) + (size_t)b * 8192;
    const float* pw   = (isQ ? pq_w : pk_w) + (size_t)c * 8192;
    const float* bias = isQ ? sqb : skb;

    float bl[MM];
    #pragma unroll
    for (int m = 0; m < MM; ++m) bl[m] = bias[m];

    int t = threadIdx.x;
    float acc = 0.f;
    #pragma unroll
    for (int i = 0; i < 8; ++i) {
        int e = i*256 + t;               // float4 index, 0..2047
        int m = (e >> 4) & 7;            // all 4 elems of this float4 share m
        float4 x = *reinterpret_cast<const float4*>(xs + (size_t)e * 4);
        float4 w = *reinterpret_cast<const float4*>(pw + (size_t)e * 4);
        float bm = bl[m];
        acc = fmaf(x.x + bm, w.x, acc);
        acc = fmaf(x.y + bm, w.y, acc);
        acc = fmaf(x.z + bm, w.z, acc);
        acc = fmaf(x.w + bm, w.w, acc);
    }
    #pragma unroll
    for (int off = 1; off < 64; off <<= 1) acc += __shfl_xor(acc, off);
    int wave = t >> 6, lane = t & 63;
    if (lane == 0) red[wave] = acc;
    __syncthreads();
    if (t == 0) {
        float total = red[0] + red[1] + red[2] + red[3];
        float pb = (isQ ? pq_b : pk_b)[c];
        float r  = total + pb;
        dots[idx] = r > 0.f ? r : 0.f;   // relu
    }
}

// ---------------------------------------------------------------------------
// Kernel 3: final tiny cluster / loss math.  1 block, 64 threads.
// ---------------------------------------------------------------------------
__global__ __launch_bounds__(64) void final_kernel(
    const float* __restrict__ dots,
    const float* __restrict__ qp_w, const float* __restrict__ qp_b,
    const float* __restrict__ kp_w, const float* __restrict__ kp_b,
    float* __restrict__ out_loss)
{
    __shared__ float s_dots[24];
    __shared__ float s_qpw[9], s_qpb[3], s_kpw[9], s_kpb[3];
    int t = threadIdx.x;
    if (t < 24) s_dots[t] = dots[t];
    if (t < 9)  { s_qpw[t] = qp_w[t]; s_kpw[t] = kp_w[t]; }
    if (t < 3)  { s_qpb[t] = qp_b[t]; s_kpb[t] = kp_b[t]; }
    __syncthreads();

    if (t == 0) {
        float cq[BB][NCC], ck[BB][NCC];
        for (int b = 0; b < BB; ++b) {
            float lq[NCC], lk[NCC];
            for (int c = 0; c < NCC; ++c) {
                float sq = s_qpb[c], sk = s_kpb[c];
                for (int c2 = 0; c2 < NCC; ++c2) {
                    sq = fmaf(s_dots[12 + b*NCC + c2], s_qpw[c*NCC + c2], sq);
                    sk = fmaf(s_dots[b*NCC + c2],      s_kpw[c*NCC + c2], sk);
                }
                lq[c] = sq; lk[c] = sk;
            }
            float mq = fmaxf(fmaxf(lq[0], lq[1]), lq[2]);
            float mk = fmaxf(fmaxf(lk[0], lk[1]), lk[2]);
            float zq = 0.f, zk = 0.f;
            for (int c = 0; c < NCC; ++c) {
                cq[b][c] = expf(lq[c] - mq); zq += cq[b][c];
                ck[b][c] = expf(lk[c] - mk); zk += ck[b][c];
            }
            for (int c = 0; c < NCC; ++c) { cq[b][c] /= zq; ck[b][c] /= zk; }
        }
        // mu = mean_b cluster_q ; sigma = softplus(std_b(cluster_k, ddof=1))
        float mu[NCC], mk_[NCC], sigma[NCC];
        for (int c = 0; c < NCC; ++c) {
            float s1 = 0.f, s2 = 0.f;
            for (int b = 0; b < BB; ++b) { s1 += cq[b][c]; s2 += ck[b][c]; }
            mu[c]  = s1 * 0.25f;
            mk_[c] = s2 * 0.25f;
        }
        for (int c = 0; c < NCC; ++c) {
            float v = 0.f;
            for (int b = 0; b < BB; ++b) {
                float d = ck[b][c] - mk_[c];
                v = fmaf(d, d, v);
            }
            float stdv = sqrtf(v / (BB - 1));
            sigma[c] = log1pf(expf(stdv));   // softplus
        }
        const float HALF_LOG_2PI = 0.9189385332046727f;
        float sum_logp = 0.f;
        for (int b = 0; b < BB; ++b)
            for (int c = 0; c < NCC; ++c) {
                float z = (ck[b][c] - mu[c]) / sigma[c];
                sum_logp += -0.5f*z*z - logf(sigma[c]) - HALF_LOG_2PI;
            }
        // ce = mean_b( -sum_c cq*log_softmax(cq) )
        float ce = 0.f;
        for (int b = 0; b < BB; ++b) {
            float mx = fmaxf(fmaxf(cq[b][0], cq[b][1]), cq[b][2]);
            float z = 0.f;
            for (int c = 0; c < NCC; ++c) z += expf(cq[b][c] - mx);
            float lse = mx + logf(z);
            float s = 0.f;
            for (int c = 0; c < NCC; ++c) s += cq[b][c] * (cq[b][c] - lse);
            ce += -s;
        }
        ce *= 0.25f;
        float loss = -(sum_logp / (BB * NCC)) + ce;
        out_loss[0] = loss;
    }
}

// ---------------------------------------------------------------------------
// Kernel 4: broadcast context.  attn == 1/8 uniformly =>
//   ctx[b,h,l,d] = (1/8) * sum_m (Vs_sum[b,h,m,d] + svb[m])   (same for all l)
// grid = 64 * 16 = 1024 blocks, 256 threads; each block writes 256 l-rows.
// ---------------------------------------------------------------------------
__global__ __launch_bounds__(256) void broadcast_kernel(
    const float* __restrict__ ws, const float* __restrict__ svb,
    float* __restrict__ out)
{
    int bx = blockIdx.x;
    int bh = bx >> 4;
    int lc = bx & 15;
    int t  = threadIdx.x;
    int d4     = (t & 15) * 4;
    int stripe = t >> 4;

    const float* vs = ws + ((size_t)1 * BH + bh) * 512;   // V partition
    float bias = 0.f;
    #pragma unroll
    for (int m = 0; m < MM; ++m) bias += svb[m];
    bias *= 0.125f;

    float4 c = make_float4(bias, bias, bias, bias);
    #pragma unroll
    for (int m = 0; m < MM; ++m) {
        c.x += 0.125f * vs[m*64 + d4 + 0];
        c.y += 0.125f * vs[m*64 + d4 + 1];
        c.z += 0.125f * vs[m*64 + d4 + 2];
        c.w += 0.125f * vs[m*64 + d4 + 3];
    }

    float* obase = out + (size_t)bh * LL * DKK + (size_t)lc * 256 * DKK;
    #pragma unroll
    for (int i = 0; i < 16; ++i) {
        int l = i*16 + stripe;
        *reinterpret_cast<float4*>(obase + (size_t)l * DKK + d4) = c;
    }
}

// ---------------------------------------------------------------------------
extern "C" void kernel_launch(void* const* d_in, const int* in_sizes, int n_in,
                              void* d_out, int out_size, void* d_ws, size_t ws_size,
                              hipStream_t stream) {
    const float* Q    = (const float*)d_in[0];
    const float* K    = (const float*)d_in[1];
    const float* V    = (const float*)d_in[2];
    const float* skw  = (const float*)d_in[3];
    const float* skb  = (const float*)d_in[4];
    const float* svw  = (const float*)d_in[5];
    const float* svb  = (const float*)d_in[6];
    const float* sqw  = (const float*)d_in[7];
    const float* sqb  = (const float*)d_in[8];
    const float* pk_w = (const float*)d_in[9];
    const float* pk_b = (const float*)d_in[10];
    const float* pq_w = (const float*)d_in[11];
    const float* pq_b = (const float*)d_in[12];
    const float* qp_w = (const float*)d_in[13];
    const float* qp_b = (const float*)d_in[14];
    const float* kp_w = (const float*)d_in[15];
    const float* kp_b = (const float*)d_in[16];

    float* out = (float*)d_out;
    float* ws  = (float*)d_ws;

    // zero the atomic accumulators (ws is poisoned 0xAA before every call)
    hipMemsetAsync(ws, 0, (size_t)3 * BH * 512 * sizeof(float), stream);

    shrink_kernel<<<dim3(3 * BH * NCHUNK), dim3(256), 0, stream>>>(
        Q, K, V, skw, svw, sqw, ws);

    dot_kernel<<<dim3(24), dim3(256), 0, stream>>>(
        ws, skb, sqb, pk_w, pk_b, pq_w, pq_b, ws + DOTS_OFF);

    final_kernel<<<dim3(1), dim3(64), 0, stream>>>(
        ws + DOTS_OFF, qp_w, qp_b, kp_w, kp_b, out + (size_t)CTX_ELEMS);

    broadcast_kernel<<<dim3(BH * 16), dim3(256), 0, stream>>>(ws, svb, out);
}

// Round 6
// 262.997 us; speedup vs baseline: 1.7309x; 1.0526x over previous
//
#include <hip/hip_runtime.h>
#include <hip/hip_bf16.h>
#include <math.h>

// Problem constants
#define BB   4
#define HH   16
#define LL   4096
#define DKK  64
#define MM   8      // LOG_LK == LOG_L
#define NCC  3
#define BH   (BB*HH)            // 64
#define NCHUNK 4
#define ROWS_PER_CHUNK (LL/NCHUNK)   // 1024
#define CTX_ELEMS (BB*HH*LL*DKK)     // 16777216

// ws layout (floats):
//   [0 .. 393215]  : [3][BH][NCHUNK][8][64] per-chunk shrink partial sums (0=K,1=V,2=Q)
//   [393216..+23]  : 24 relu'd cluster dot products (12 K-path, 12 Q-path)
#define DOTS_OFF (3*BH*NCHUNK*512)   // 393216

// ---------------------------------------------------------------------------
// Kernel 1: shrink reductions, chunked over k.  For X in {K,V,Q}:
//   ws[x][bh][chunk][m][d] = sum_{k in chunk} X[bh][k][d] * w[m][k]
// grid = 3*64*4 = 768 blocks, 256 threads.  No atomics, no memset needed.
// LDS: weights [m][k] 32KB (conflict-free both sides), red buffer aliased.
// ---------------------------------------------------------------------------
__global__ __launch_bounds__(256, 5) void shrink_kernel(
    const float* __restrict__ Q, const float* __restrict__ K,
    const float* __restrict__ V,
    const float* __restrict__ skw, const float* __restrict__ svw,
    const float* __restrict__ sqw,
    float* __restrict__ ws)
{
    __shared__ float wlds[MM * ROWS_PER_CHUNK];   // 32KB; red aliases after main loop
    float* red = wlds;                            // [4 waves][16 dg][33] = 2112 floats

    int bx    = blockIdx.x;
    int input = bx >> 8;                // 0=K, 1=V, 2=Q   (bx / 256)
    int rem   = bx & 255;
    int bh    = rem >> 2;
    int chunk = rem & 3;

    const float* X; const float* W;
    if (input == 0)      { X = K; W = skw; }
    else if (input == 1) { X = V; W = svw; }
    else                 { X = Q; W = sqw; }

    int t  = threadIdx.x;
    int k0 = chunk * ROWS_PER_CHUNK;

    // stage weights in [m][k] layout: coalesced global reads, conflict-free LDS
    #pragma unroll
    for (int m = 0; m < MM; ++m)
        #pragma unroll
        for (int kk = 0; kk < ROWS_PER_CHUNK; kk += 256)
            wlds[m*ROWS_PER_CHUNK + kk + t] = W[m*LL + k0 + kk + t];
    __syncthreads();

    int dg     = t & 15;          // d-group: 4 consecutive d columns
    int d4     = dg * 4;
    int stripe = t >> 4;          // 0..15

    const float* base = X + (size_t)bh * LL * DKK + (size_t)k0 * DKK;

    float4 acc[MM];
    #pragma unroll
    for (int m = 0; m < MM; ++m) acc[m] = make_float4(0.f, 0.f, 0.f, 0.f);

    // rows = j*64 + u*16 + stripe; each wave's load is 1KB contiguous; 4 in flight
    for (int j = 0; j < ROWS_PER_CHUNK/64; ++j) {     // 16 iterations
        float4 v[4];
        #pragma unroll
        for (int u = 0; u < 4; ++u) {
            int row = j*64 + u*16 + stripe;
            v[u] = *reinterpret_cast<const float4*>(base + (size_t)row * DKK + d4);
        }
        #pragma unroll
        for (int u = 0; u < 4; ++u) {
            int row = j*64 + u*16 + stripe;
            #pragma unroll
            for (int m = 0; m < MM; ++m) {
                float w = wlds[m*ROWS_PER_CHUNK + row];   // 16-lane broadcast, 4 banks/wave
                acc[m].x = fmaf(v[u].x, w, acc[m].x);
                acc[m].y = fmaf(v[u].y, w, acc[m].y);
                acc[m].z = fmaf(v[u].z, w, acc[m].z);
                acc[m].w = fmaf(v[u].w, w, acc[m].w);
            }
        }
    }

    // wave-level reduction over the 4 stripes this wave owns (lanes l, l^16, l^32, l^48)
    #pragma unroll
    for (int m = 0; m < MM; ++m) {
        acc[m].x += __shfl_xor(acc[m].x, 16);
        acc[m].y += __shfl_xor(acc[m].y, 16);
        acc[m].z += __shfl_xor(acc[m].z, 16);
        acc[m].w += __shfl_xor(acc[m].w, 16);
        acc[m].x += __shfl_xor(acc[m].x, 32);
        acc[m].y += __shfl_xor(acc[m].y, 32);
        acc[m].z += __shfl_xor(acc[m].z, 32);
        acc[m].w += __shfl_xor(acc[m].w, 32);
    }

    __syncthreads();   // main-loop LDS reads done; safe to reuse wlds as red

    int wave = t >> 6, lane = t & 63;
    if (lane < 16) {
        float* r = &red[(wave*16 + lane) * 33];   // pad 33 -> staggered banks
        #pragma unroll
        for (int m = 0; m < MM; ++m) {
            r[m*4 + 0] = acc[m].x;
            r[m*4 + 1] = acc[m].y;
            r[m*4 + 2] = acc[m].z;
            r[m*4 + 3] = acc[m].w;
        }
    }
    __syncthreads();

    // 512 outputs (m,d), coalesced plain stores (per-chunk slot, no atomic)
    float* wsb = ws + (size_t)(((input*BH + bh)*NCHUNK + chunk)) * 512;
    for (int o = t; o < 512; o += 256) {
        int m = o >> 6, d = o & 63;
        int dgg = d >> 2, dc = d & 3;
        float s = 0.f;
        #pragma unroll
        for (int w = 0; w < 4; ++w)
            s += red[(w*16 + dgg)*33 + m*4 + dc];
        wsb[o] = s;
    }
}

// ---------------------------------------------------------------------------
// Kernel 2: 24 cluster dot-products, one block each (sums the 4 chunks).
//   idx < 12:  K-path  (b=idx/3, c=idx%3): relu( (Ks+skb) . pk_w[c] + pk_b[c] )
//   idx >= 12: Q-path with sqb/pq_w/pq_b
// Dot over [h=16][m=8][d=64]; bias depends on m only.
// ---------------------------------------------------------------------------
__global__ __launch_bounds__(256) void dot_kernel(
    const float* __restrict__ ws,
    const float* __restrict__ skb, const float* __restrict__ sqb,
    const float* __restrict__ pk_w, const float* __restrict__ pk_b,
    const float* __restrict__ pq_w, const float* __restrict__ pq_b,
    float* __restrict__ dots)
{
    __shared__ float red[4];
    int idx = blockIdx.x;
    int isQ = idx >= 12;
    int g   = idx - (isQ ? 12 : 0);
    int b   = g / NCC;
    int c   = g % NCC;

    int input = isQ ? 2 : 0;
    const float* pw   = (isQ ? pq_w : pk_w) + (size_t)c * 8192;
    const float* bias = isQ ? sqb : skb;

    float bl[MM];
    #pragma unroll
    for (int m = 0; m < MM; ++m) bl[m] = bias[m];

    int t = threadIdx.x;
    float acc = 0.f;
    #pragma unroll
    for (int i = 0; i < 8; ++i) {
        int e = i*256 + t;               // float4 index, 0..2047 over [h][m][d]
        int h = e >> 7;
        int m = (e >> 4) & 7;
        const float* xb = ws + (size_t)(((input*BH + b*HH + h)*NCHUNK)) * 512
                             + (size_t)(e & 127) * 4;
        float4 x = make_float4(0.f, 0.f, 0.f, 0.f);
        #pragma unroll
        for (int ch = 0; ch < NCHUNK; ++ch) {
            float4 p = *reinterpret_cast<const float4*>(xb + ch*512);
            x.x += p.x; x.y += p.y; x.z += p.z; x.w += p.w;
        }
        float4 w = *reinterpret_cast<const float4*>(pw + (size_t)e * 4);
        float bm = bl[m];
        acc = fmaf(x.x + bm, w.x, acc);
        acc = fmaf(x.y + bm, w.y, acc);
        acc = fmaf(x.z + bm, w.z, acc);
        acc = fmaf(x.w + bm, w.w, acc);
    }
    #pragma unroll
    for (int off = 1; off < 64; off <<= 1) acc += __shfl_xor(acc, off);
    int wave = t >> 6, lane = t & 63;
    if (lane == 0) red[wave] = acc;
    __syncthreads();
    if (t == 0) {
        float total = red[0] + red[1] + red[2] + red[3];
        float pb = (isQ ? pq_b : pk_b)[c];
        float r  = total + pb;
        dots[idx] = r > 0.f ? r : 0.f;   // relu
    }
}

// ---------------------------------------------------------------------------
// Kernel 3: final tiny cluster / loss math.  1 block, 64 threads.
// ---------------------------------------------------------------------------
__global__ __launch_bounds__(64) void final_kernel(
    const float* __restrict__ dots,
    const float* __restrict__ qp_w, const float* __restrict__ qp_b,
    const float* __restrict__ kp_w, const float* __restrict__ kp_b,
    float* __restrict__ out_loss)
{
    __shared__ float s_dots[24];
    __shared__ float s_qpw[9], s_qpb[3], s_kpw[9], s_kpb[3];
    int t = threadIdx.x;
    if (t < 24) s_dots[t] = dots[t];
    if (t < 9)  { s_qpw[t] = qp_w[t]; s_kpw[t] = kp_w[t]; }
    if (t < 3)  { s_qpb[t] = qp_b[t]; s_kpb[t] = kp_b[t]; }
    __syncthreads();

    if (t == 0) {
        float cq[BB][NCC], ck[BB][NCC];
        for (int b = 0; b < BB; ++b) {
            float lq[NCC], lk[NCC];
            for (int c = 0; c < NCC; ++c) {
                float sq = s_qpb[c], sk = s_kpb[c];
                for (int c2 = 0; c2 < NCC; ++c2) {
                    sq = fmaf(s_dots[12 + b*NCC + c2], s_qpw[c*NCC + c2], sq);
                    sk = fmaf(s_dots[b*NCC + c2],      s_kpw[c*NCC + c2], sk);
                }
                lq[c] = sq; lk[c] = sk;
            }
            float mq = fmaxf(fmaxf(lq[0], lq[1]), lq[2]);
            float mk = fmaxf(fmaxf(lk[0], lk[1]), lk[2]);
            float zq = 0.f, zk = 0.f;
            for (int c = 0; c < NCC; ++c) {
                cq[b][c] = expf(lq[c] - mq); zq += cq[b][c];
                ck[b][c] = expf(lk[c] - mk); zk += ck[b][c];
            }
            for (int c = 0; c < NCC; ++c) { cq[b][c] /= zq; ck[b][c] /= zk; }
        }
        // mu = mean_b cluster_q ; sigma = softplus(std_b(cluster_k, ddof=1))
        float mu[NCC], mk_[NCC], sigma[NCC];
        for (int c = 0; c < NCC; ++c) {
            float s1 = 0.f, s2 = 0.f;
            for (int b = 0; b < BB; ++b) { s1 += cq[b][c]; s2 += ck[b][c]; }
            mu[c]  = s1 * 0.25f;
            mk_[c] = s2 * 0.25f;
        }
        for (int c = 0; c < NCC; ++c) {
            float v = 0.f;
            for (int b = 0; b < BB; ++b) {
                float d = ck[b][c] - mk_[c];
                v = fmaf(d, d, v);
            }
            float stdv = sqrtf(v / (BB - 1));
            sigma[c] = log1pf(expf(stdv));   // softplus
        }
        const float HALF_LOG_2PI = 0.9189385332046727f;
        float sum_logp = 0.f;
        for (int b = 0; b < BB; ++b)
            for (int c = 0; c < NCC; ++c) {
                float z = (ck[b][c] - mu[c]) / sigma[c];
                sum_logp += -0.5f*z*z - logf(sigma[c]) - HALF_LOG_2PI;
            }
        // ce = mean_b( -sum_c cq*log_softmax(cq) )
        float ce = 0.f;
        for (int b = 0; b < BB; ++b) {
            float mx = fmaxf(fmaxf(cq[b][0], cq[b][1]), cq[b][2]);
            float z = 0.f;
            for (int c = 0; c < NCC; ++c) z += expf(cq[b][c] - mx);
            float lse = mx + logf(z);
            float s = 0.f;
            for (int c = 0; c < NCC; ++c) s += cq[b][c] * (cq[b][c] - lse);
            ce += -s;
        }
        ce *= 0.25f;
        float loss = -(sum_logp / (BB * NCC)) + ce;
        out_loss[0] = loss;
    }
}

// ---------------------------------------------------------------------------
// Kernel 4: broadcast context.  attn == 1/8 uniformly =>
//   ctx[b,h,l,d] = (1/8) * sum_m (Vs_sum[b,h,m,d] + svb[m])   (same for all l)
// grid = 64 * 16 = 1024 blocks, 256 threads; each block writes 256 l-rows.
// ---------------------------------------------------------------------------
__global__ __launch_bounds__(256) void broadcast_kernel(
    const float* __restrict__ ws, const float* __restrict__ svb,
    float* __restrict__ out)
{
    int bx = blockIdx.x;
    int bh = bx >> 4;
    int lc = bx & 15;
    int t  = threadIdx.x;
    int d4     = (t & 15) * 4;
    int stripe = t >> 4;

    const float* vsb = ws + (size_t)((1*BH + bh)*NCHUNK) * 512;   // V partition
    float bias = 0.f;
    #pragma unroll
    for (int m = 0; m < MM; ++m) bias += svb[m];
    bias *= 0.125f;

    float4 c = make_float4(bias, bias, bias, bias);
    #pragma unroll
    for (int m = 0; m < MM; ++m) {
        #pragma unroll
        for (int ch = 0; ch < NCHUNK; ++ch) {
            const float* p = vsb + ch*512 + m*64 + d4;
            c.x += 0.125f * p[0];
            c.y += 0.125f * p[1];
            c.z += 0.125f * p[2];
            c.w += 0.125f * p[3];
        }
    }

    float* obase = out + (size_t)bh * LL * DKK + (size_t)lc * 256 * DKK;
    #pragma unroll
    for (int i = 0; i < 16; ++i) {
        int l = i*16 + stripe;
        *reinterpret_cast<float4*>(obase + (size_t)l * DKK + d4) = c;
    }
}

// ---------------------------------------------------------------------------
extern "C" void kernel_launch(void* const* d_in, const int* in_sizes, int n_in,
                              void* d_out, int out_size, void* d_ws, size_t ws_size,
                              hipStream_t stream) {
    const float* Q    = (const float*)d_in[0];
    const float* K    = (const float*)d_in[1];
    const float* V    = (const float*)d_in[2];
    const float* skw  = (const float*)d_in[3];
    const float* skb  = (const float*)d_in[4];
    const float* svw  = (const float*)d_in[5];
    const float* svb  = (const float*)d_in[6];
    const float* sqw  = (const float*)d_in[7];
    const float* sqb  = (const float*)d_in[8];
    const float* pk_w = (const float*)d_in[9];
    const float* pk_b = (const float*)d_in[10];
    const float* pq_w = (const float*)d_in[11];
    const float* pq_b = (const float*)d_in[12];
    const float* qp_w = (const float*)d_in[13];
    const float* qp_b = (const float*)d_in[14];
    const float* kp_w = (const float*)d_in[15];
    const float* kp_b = (const float*)d_in[16];

    float* out = (float*)d_out;
    float* ws  = (float*)d_ws;

    // no memset needed: every ws slot consumed is written by shrink/dot first

    shrink_kernel<<<dim3(3 * BH * NCHUNK), dim3(256), 0, stream>>>(
        Q, K, V, skw, svw, sqw, ws);

    dot_kernel<<<dim3(24), dim3(256), 0, stream>>>(
        ws, skb, sqb, pk_w, pk_b, pq_w, pq_b, ws + DOTS_OFF);

    final_kernel<<<dim3(1), dim3(64), 0, stream>>>(
        ws + DOTS_OFF, qp_w, qp_b, kp_w, kp_b, out + (size_t)CTX_ELEMS);

    broadcast_kernel<<<dim3(BH * 16), dim3(256), 0, stream>>>(ws, svb, out);
}